// Round 2
// baseline (506.288 us; speedup 1.0000x reference)
//
#include <hip/hip_runtime.h>
#include <hip/hip_bf16.h>

#define BB 4
#define SS 2048
#define DDIM 1024
#define HH 16
#define MTOT (BB*SS)   // 8192

typedef __attribute__((ext_vector_type(8))) __bf16 bf16x8;
typedef __attribute__((ext_vector_type(4))) float f32x4;

static __device__ __forceinline__ unsigned short f2bf(float f) {
  union { float f; unsigned u; } v; v.f = f;
  unsigned r = v.u + 0x7FFFu + ((v.u >> 16) & 1u);
  return (unsigned short)(r >> 16);
}

// alias-safe 16B load (ds_read_b128 / global_load_dwordx4)
static __device__ __forceinline__ bf16x8 ld_bf16x8(const void* p) {
  bf16x8 r;
  __builtin_memcpy(&r, p, 16);
  return r;
}

static __device__ __forceinline__ void gload_lds16(const void* g, void* l) {
  __builtin_amdgcn_global_load_lds(
      (const __attribute__((address_space(1))) unsigned int*)g,
      (__attribute__((address_space(3))) unsigned int*)l, 16, 0, 0);
}

// ---------------- RoPE tables: cos/sin [2048][32] fp32 ----------------
__global__ void k_rope_tables(float* __restrict__ tc, float* __restrict__ ts) {
  int i = blockIdx.x * 256 + threadIdx.x;   // 65536 total
  int s = i >> 5, d = i & 31;
  float inv = powf(10000.0f, -((float)d) / 32.0f);
  float a = (float)s * inv;
  tc[i] = cosf(a);
  ts[i] = sinf(a);
}

// ---------------- fp32 -> bf16 convert, 4 elems/thread ----------------
__global__ void k_cvt_bf16(const float* __restrict__ in,
                           unsigned short* __restrict__ out, int n4) {
  int i = blockIdx.x * 256 + threadIdx.x;
  if (i >= n4) return;
  float4 v = ((const float4*)in)[i];
  ushort4 o;
  o.x = f2bf(v.x); o.y = f2bf(v.y); o.z = f2bf(v.z); o.w = f2bf(v.w);
  ((ushort4*)out)[i] = o;
}

// ---------------- GEMM: C[M][1024] = A[M][1024] * Bw[1024][1024]^T + bias ----
// 128x128 tile, BK=64, 4 waves (each 64x64), XOR-swizzled LDS (T2),
// global_load_lds width-16 staging with pre-swizzled global source.
#define E_ROPE 0
#define E_VT   1
#define E_F32  2

template<int EPI>
__global__ __launch_bounds__(256, 2) void k_gemm(
    const unsigned short* __restrict__ A,    // bf16 [M][1024]
    const unsigned short* __restrict__ Bw,   // bf16 [1024][1024] (row n, k contig)
    const float* __restrict__ bias,          // [1024]
    void* __restrict__ out,
    const float* __restrict__ tc, const float* __restrict__ ts,
    float scale)
{
  __shared__ unsigned short As[128*64];
  __shared__ unsigned short Bs[128*64];
  const int tid  = threadIdx.x;
  const int lane = tid & 63;
  const int wv   = tid >> 6;
  const int wr   = wv >> 1, wc = wv & 1;
  const int l15  = lane & 15, l4 = lane >> 4;
  const int bm0  = blockIdx.x * 128;
  const int bn0  = blockIdx.y * 128;

  const f32x4 fz = {0.f, 0.f, 0.f, 0.f};
  f32x4 acc[4][4];
#pragma unroll
  for (int m = 0; m < 4; ++m)
#pragma unroll
    for (int n = 0; n < 4; ++n) acc[m][n] = fz;

  // staging geometry: chunk c = wv*4+i covers rows c*8..c*8+7 (1KB linear LDS)
  const int srow = lane >> 3;            // 0..7 within chunk
  const int scol = ((lane & 7) ^ srow) * 8;  // pre-swizzled source column (shorts)

  for (int kt = 0; kt < 16; ++kt) {
    const int k0 = kt * 64;
#pragma unroll
    for (int i = 0; i < 4; ++i) {
      const int c = wv * 4 + i;
      const int row = c * 8 + srow;
      gload_lds16(A  + (size_t)(bm0 + row) * 1024 + k0 + scol, (char*)As + c * 1024);
      gload_lds16(Bw + (size_t)(bn0 + row) * 1024 + k0 + scol, (char*)Bs + c * 1024);
    }
    __syncthreads();
#pragma unroll
    for (int h = 0; h < 2; ++h) {
      bf16x8 af[4], bfr[4];
#pragma unroll
      for (int m = 0; m < 4; ++m) {
        const int row = 64 * wr + 16 * m + l15;
        const int sl = ((l4 + 4 * h) ^ (l15 & 7)) * 8;
        af[m] = ld_bf16x8(&As[row * 64 + sl]);
      }
#pragma unroll
      for (int n = 0; n < 4; ++n) {
        const int row = 64 * wc + 16 * n + l15;
        const int sl = ((l4 + 4 * h) ^ (l15 & 7)) * 8;
        bfr[n] = ld_bf16x8(&Bs[row * 64 + sl]);
      }
#pragma unroll
      for (int m = 0; m < 4; ++m)
#pragma unroll
        for (int n = 0; n < 4; ++n)
          acc[m][n] = __builtin_amdgcn_mfma_f32_16x16x32_bf16(af[m], bfr[n], acc[m][n], 0, 0, 0);
    }
    __syncthreads();
  }

  if (EPI == E_ROPE) {
    unsigned short* O = (unsigned short*)out;
#pragma unroll
    for (int m = 0; m < 4; ++m) {
      const int row0 = bm0 + 64 * wr + 16 * m + 4 * l4;
#pragma unroll
      for (int n = 0; n < 2; ++n) {
        const int d = 16 * n + l15;            // 0..31
        const int col1 = bn0 + 64 * wc + d;
        const float b1 = bias[col1], b2 = bias[col1 + 32];
#pragma unroll
        for (int i = 0; i < 4; ++i) {
          const int row = row0 + i;
          const int s = row & (SS - 1);
          const float c = tc[s * 32 + d], sn = ts[s * 32 + d];
          const float x1 = acc[m][n][i] + b1;
          const float x2 = acc[m][n + 2][i] + b2;
          O[(size_t)row * 1024 + col1]      = f2bf((x1 * c - x2 * sn) * scale);
          O[(size_t)row * 1024 + col1 + 32] = f2bf((x1 * sn + x2 * c) * scale);
        }
      }
    }
  } else if (EPI == E_VT) {
    // write V transposed: vT[b][h][d][s], bf16
    unsigned short* O = (unsigned short*)out;
    const int hh = (bn0 + 64 * wc) >> 6;
#pragma unroll
    for (int m = 0; m < 4; ++m) {
      const int row0 = bm0 + 64 * wr + 16 * m + 4 * l4;
      const int b_ = row0 >> 11;
      const int s0 = row0 & (SS - 1);
#pragma unroll
      for (int n = 0; n < 4; ++n) {
        const int d = 16 * n + l15;
        const float bb = bias[bn0 + 64 * wc + d];
        ushort4 o;
        o.x = f2bf(acc[m][n][0] + bb);
        o.y = f2bf(acc[m][n][1] + bb);
        o.z = f2bf(acc[m][n][2] + bb);
        o.w = f2bf(acc[m][n][3] + bb);
        *(ushort4*)&O[((size_t)(b_ * HH + hh) * 64 + d) * SS + s0] = o;
      }
    }
  } else {
    float* O = (float*)out;
#pragma unroll
    for (int m = 0; m < 4; ++m) {
      const int row0 = bm0 + 64 * wr + 16 * m + 4 * l4;
#pragma unroll
      for (int n = 0; n < 4; ++n) {
        const int col = bn0 + 64 * wc + 16 * n + l15;
        const float bb = bias[col];
#pragma unroll
        for (int i = 0; i < 4; ++i)
          O[(size_t)(row0 + i) * 1024 + col] = acc[m][n][i] + bb;
      }
    }
  }
}

// ---------------- causal flash attention -----------------------------
// grid: (B*H)*(S/64) blocks; 4 waves, wave wv owns q rows [16wv,16wv+16).
// q pre-scaled by 0.125*log2e in its RoPE epilogue -> exp2f softmax.
__global__ __launch_bounds__(256, 2) void k_attn(
    const unsigned short* __restrict__ qr,   // bf16 [8192][1024] (token major)
    const unsigned short* __restrict__ kr,   // bf16 [8192][1024]
    const unsigned short* __restrict__ vT,   // bf16 [64 bh][64 d][2048 s]
    unsigned short* __restrict__ ao)         // bf16 [8192][1024]
{
  __shared__ unsigned short Ks[64*64];
  __shared__ unsigned short Vs[64*64];
  __shared__ unsigned short Ps[4][16*64];
  const int tid = threadIdx.x, lane = tid & 63, wv = tid >> 6;
  const int l15 = lane & 15, l4 = lane >> 4;
  const int qb = blockIdx.x & 31;
  const int bh = blockIdx.x >> 5;
  const int b_ = bh >> 4, h_ = bh & 15;
  const int q0 = qb * 64;

  const size_t qoff = ((size_t)(b_ * SS + q0 + 16 * wv + l15)) * 1024 + h_ * 64 + l4 * 8;
  const bf16x8 aq0 = ld_bf16x8(&qr[qoff]);
  const bf16x8 aq1 = ld_bf16x8(&qr[qoff + 32]);

  const f32x4 fz = {0.f, 0.f, 0.f, 0.f};
  f32x4 accO[4];
#pragma unroll
  for (int dt = 0; dt < 4; ++dt) accO[dt] = fz;
  float mrun[4], lrun[4];
#pragma unroll
  for (int i = 0; i < 4; ++i) { mrun[i] = -1e30f; lrun[i] = 0.f; }

  const int srow = lane >> 3;
  const int scol = ((lane & 7) ^ srow) * 8;

  for (int kt = 0; kt <= qb; ++kt) {
    const int k0 = kt * 64;
#pragma unroll
    for (int i = 0; i < 2; ++i) {
      const int c = wv * 2 + i;
      const int row = c * 8 + srow;
      gload_lds16(kr + ((size_t)(b_ * SS + k0 + row)) * 1024 + h_ * 64 + scol,
                  (char*)Ks + c * 1024);
      gload_lds16(vT + ((size_t)(bh * 64 + row)) * SS + k0 + scol,
                  (char*)Vs + c * 1024);
    }
    __syncthreads();

    f32x4 sc[4];
#pragma unroll
    for (int n = 0; n < 4; ++n) {
      const int row = 16 * n + l15;
      const int sl0 = ((l4 + 0) ^ (l15 & 7)) * 8;
      const int sl1 = ((l4 + 4) ^ (l15 & 7)) * 8;
      bf16x8 kf0 = ld_bf16x8(&Ks[row * 64 + sl0]);
      bf16x8 kf1 = ld_bf16x8(&Ks[row * 64 + sl1]);
      sc[n] = __builtin_amdgcn_mfma_f32_16x16x32_bf16(aq0, kf0, fz, 0, 0, 0);
      sc[n] = __builtin_amdgcn_mfma_f32_16x16x32_bf16(aq1, kf1, sc[n], 0, 0, 0);
    }
    if (kt == qb) {
#pragma unroll
      for (int n = 0; n < 4; ++n)
#pragma unroll
        for (int i = 0; i < 4; ++i) {
          const int kj = 16 * n + l15;
          const int qi = 16 * wv + 4 * l4 + i;
          if (kj > qi) sc[n][i] = -1e30f;
        }
    }
    float pn[4][4];
#pragma unroll
    for (int i = 0; i < 4; ++i) {
      float t = fmaxf(fmaxf(sc[0][i], sc[1][i]), fmaxf(sc[2][i], sc[3][i]));
      t = fmaxf(t, __shfl_xor(t, 1));
      t = fmaxf(t, __shfl_xor(t, 2));
      t = fmaxf(t, __shfl_xor(t, 4));
      t = fmaxf(t, __shfl_xor(t, 8));
      const float mn = fmaxf(mrun[i], t);
      const float alpha = exp2f(mrun[i] - mn);
      mrun[i] = mn;
      float rs = 0.f;
#pragma unroll
      for (int n = 0; n < 4; ++n) { pn[n][i] = exp2f(sc[n][i] - mn); rs += pn[n][i]; }
      rs += __shfl_xor(rs, 1);
      rs += __shfl_xor(rs, 2);
      rs += __shfl_xor(rs, 4);
      rs += __shfl_xor(rs, 8);
      lrun[i] = lrun[i] * alpha + rs;
#pragma unroll
      for (int dt = 0; dt < 4; ++dt) accO[dt][i] *= alpha;
    }
    // P -> bf16 -> per-wave swizzled LDS tile [16 q][64 kj]
#pragma unroll
    for (int n = 0; n < 4; ++n)
#pragma unroll
      for (int i = 0; i < 4; ++i) {
        const int r = 4 * l4 + i;
        const int cc = 16 * n + l15;
        const int phys = (cc >> 3) ^ (r & 7);
        Ps[wv][r * 64 + phys * 8 + (cc & 7)] = f2bf(pn[n][i]);
      }
#pragma unroll
    for (int kk = 0; kk < 2; ++kk) {
      const int psl = ((l4 + 4 * kk) ^ (l15 & 7)) * 8;
      bf16x8 pa = ld_bf16x8(&Ps[wv][l15 * 64 + psl]);
#pragma unroll
      for (int dt = 0; dt < 4; ++dt) {
        const int row = 16 * dt + l15;
        const int vsl = ((l4 + 4 * kk) ^ (l15 & 7)) * 8;
        bf16x8 vb = ld_bf16x8(&Vs[row * 64 + vsl]);
        accO[dt] = __builtin_amdgcn_mfma_f32_16x16x32_bf16(pa, vb, accO[dt], 0, 0, 0);
      }
    }
    __syncthreads();
  }
#pragma unroll
  for (int i = 0; i < 4; ++i) {
    const float inv = 1.0f / lrun[i];
    const size_t row = (size_t)(b_ * SS + q0 + 16 * wv + 4 * l4 + i);
#pragma unroll
    for (int dt = 0; dt < 4; ++dt)
      ao[row * 1024 + h_ * 64 + 16 * dt + l15] = f2bf(accO[dt][i] * inv);
  }
}

extern "C" void kernel_launch(void* const* d_in, const int* in_sizes, int n_in,
                              void* d_out, int out_size, void* d_ws, size_t ws_size,
                              hipStream_t stream) {
  const float* Q  = (const float*)d_in[0];
  const float* K  = (const float*)d_in[1];
  const float* V  = (const float*)d_in[2];
  const float* Wq = (const float*)d_in[3];
  const float* bq = (const float*)d_in[4];
  const float* Wk = (const float*)d_in[5];
  const float* bk = (const float*)d_in[6];
  const float* Wv = (const float*)d_in[7];
  const float* bv = (const float*)d_in[8];
  const float* Wo = (const float*)d_in[9];
  const float* bo = (const float*)d_in[10];
  float* out = (float*)d_out;

  char* ws = (char*)d_ws;
  float* tc = (float*)(ws);
  float* ts = (float*)(ws + 256 * 1024);
  unsigned short* wqb = (unsigned short*)(ws + 512 * 1024);
  unsigned short* wkb = wqb + (1u << 20);
  unsigned short* wvb = wkb + (1u << 20);
  unsigned short* wob = wvb + (1u << 20);
  unsigned short* xb  = wob + (1u << 20);
  unsigned short* qrb = xb  + (size_t)MTOT * 1024;
  unsigned short* krb = qrb + (size_t)MTOT * 1024;
  unsigned short* vtb = krb + (size_t)MTOT * 1024;
  unsigned short* aob = vtb + (size_t)MTOT * 1024;

  k_rope_tables<<<256, 256, 0, stream>>>(tc, ts);
  k_cvt_bf16<<<1024, 256, 0, stream>>>(Wq, wqb, 1024 * 1024 / 4);
  k_cvt_bf16<<<1024, 256, 0, stream>>>(Wk, wkb, 1024 * 1024 / 4);
  k_cvt_bf16<<<1024, 256, 0, stream>>>(Wv, wvb, 1024 * 1024 / 4);
  k_cvt_bf16<<<1024, 256, 0, stream>>>(Wo, wob, 1024 * 1024 / 4);

  dim3 gg(MTOT / 128, 8);
  const float qsc = 0.125f * 1.4426950408889634f;  // fold 1/sqrt(64) and log2e

  k_cvt_bf16<<<MTOT * 1024 / 4 / 256, 256, 0, stream>>>(Q, xb, MTOT * 1024 / 4);
  k_gemm<E_ROPE><<<gg, 256, 0, stream>>>(xb, wqb, bq, qrb, tc, ts, qsc);
  k_cvt_bf16<<<MTOT * 1024 / 4 / 256, 256, 0, stream>>>(K, xb, MTOT * 1024 / 4);
  k_gemm<E_ROPE><<<gg, 256, 0, stream>>>(xb, wkb, bk, krb, tc, ts, 1.0f);
  k_cvt_bf16<<<MTOT * 1024 / 4 / 256, 256, 0, stream>>>(V, xb, MTOT * 1024 / 4);
  k_gemm<E_VT><<<gg, 256, 0, stream>>>(xb, wvb, bv, vtb, tc, ts, 1.0f);

  k_attn<<<64 * 32, 256, 0, stream>>>(qrb, krb, vtb, aob);

  k_gemm<E_F32><<<gg, 256, 0, stream>>>(aob, wob, bo, out, tc, ts, 1.0f);
}

// Round 3
// 390.167 us; speedup vs baseline: 1.2976x; 1.2976x over previous
//
#include <hip/hip_runtime.h>
#include <hip/hip_bf16.h>

#define BB 4
#define SS 2048
#define DDIM 1024
#define HH 16
#define MTOT (BB*SS)   // 8192

typedef __attribute__((ext_vector_type(8))) __bf16 bf16x8;
typedef __attribute__((ext_vector_type(4))) float f32x4;

static __device__ __forceinline__ unsigned short f2bf(float f) {
  union { float f; unsigned u; } v; v.f = f;
  unsigned r = v.u + 0x7FFFu + ((v.u >> 16) & 1u);
  return (unsigned short)(r >> 16);
}

// alias-safe 16B load (ds_read_b128 / global_load_dwordx4)
static __device__ __forceinline__ bf16x8 ld_bf16x8(const void* p) {
  bf16x8 r;
  __builtin_memcpy(&r, p, 16);
  return r;
}

static __device__ __forceinline__ void gload_lds16(const void* g, void* l) {
  __builtin_amdgcn_global_load_lds(
      (const __attribute__((address_space(1))) unsigned int*)g,
      (__attribute__((address_space(3))) unsigned int*)l, 16, 0, 0);
}

// ---------------- RoPE tables: cos/sin [2048][32] fp32 ----------------
__global__ void k_rope_tables(float* __restrict__ tc, float* __restrict__ ts) {
  int i = blockIdx.x * 256 + threadIdx.x;   // 65536 total
  int s = i >> 5, d = i & 31;
  float inv = powf(10000.0f, -((float)d) / 32.0f);
  float a = (float)s * inv;
  tc[i] = cosf(a);
  ts[i] = sinf(a);
}

// ---------------- fp32 -> bf16 convert, 4 elems/thread ----------------
__global__ void k_cvt_bf16(const float* __restrict__ in,
                           unsigned short* __restrict__ out, int n4) {
  int i = blockIdx.x * 256 + threadIdx.x;
  if (i >= n4) return;
  float4 v = ((const float4*)in)[i];
  ushort4 o;
  o.x = f2bf(v.x); o.y = f2bf(v.y); o.z = f2bf(v.z); o.w = f2bf(v.w);
  ((ushort4*)out)[i] = o;
}

// ---------------- GEMM: C[M][1024] = A[M][1024] * Bw[1024][1024]^T + bias ----
// 128x128 tile, BK=64, 4 waves (each 64x64), XOR-swizzled LDS (T2),
// global_load_lds width-16 staging with pre-swizzled global source.
#define E_ROPE 0
#define E_VT   1
#define E_F32  2

template<int EPI>
__global__ __launch_bounds__(256, 2) void k_gemm(
    const unsigned short* __restrict__ A,    // bf16 [M][1024]
    const unsigned short* __restrict__ Bw,   // bf16 [1024][1024] (row n, k contig)
    const float* __restrict__ bias,          // [1024]
    void* __restrict__ out,
    const float* __restrict__ tc, const float* __restrict__ ts,
    float scale)
{
  __shared__ unsigned short As[128*64];
  __shared__ unsigned short Bs[128*64];
  const int tid  = threadIdx.x;
  const int lane = tid & 63;
  const int wv   = tid >> 6;
  const int wr   = wv >> 1, wc = wv & 1;
  const int l15  = lane & 15, l4 = lane >> 4;
  const int bm0  = blockIdx.x * 128;
  const int bn0  = blockIdx.y * 128;

  const f32x4 fz = {0.f, 0.f, 0.f, 0.f};
  f32x4 acc[4][4];
#pragma unroll
  for (int m = 0; m < 4; ++m)
#pragma unroll
    for (int n = 0; n < 4; ++n) acc[m][n] = fz;

  // staging geometry: chunk c = wv*4+i covers rows c*8..c*8+7 (1KB linear LDS)
  const int srow = lane >> 3;            // 0..7 within chunk
  const int scol = ((lane & 7) ^ srow) * 8;  // pre-swizzled source column (shorts)

  for (int kt = 0; kt < 16; ++kt) {
    const int k0 = kt * 64;
#pragma unroll
    for (int i = 0; i < 4; ++i) {
      const int c = wv * 4 + i;
      const int row = c * 8 + srow;
      gload_lds16(A  + (size_t)(bm0 + row) * 1024 + k0 + scol, (char*)As + c * 1024);
      gload_lds16(Bw + (size_t)(bn0 + row) * 1024 + k0 + scol, (char*)Bs + c * 1024);
    }
    __syncthreads();
#pragma unroll
    for (int h = 0; h < 2; ++h) {
      bf16x8 af[4], bfr[4];
#pragma unroll
      for (int m = 0; m < 4; ++m) {
        const int row = 64 * wr + 16 * m + l15;
        const int sl = ((l4 + 4 * h) ^ (l15 & 7)) * 8;
        af[m] = ld_bf16x8(&As[row * 64 + sl]);
      }
#pragma unroll
      for (int n = 0; n < 4; ++n) {
        const int row = 64 * wc + 16 * n + l15;
        const int sl = ((l4 + 4 * h) ^ (l15 & 7)) * 8;
        bfr[n] = ld_bf16x8(&Bs[row * 64 + sl]);
      }
#pragma unroll
      for (int m = 0; m < 4; ++m)
#pragma unroll
        for (int n = 0; n < 4; ++n)
          acc[m][n] = __builtin_amdgcn_mfma_f32_16x16x32_bf16(af[m], bfr[n], acc[m][n], 0, 0, 0);
    }
    __syncthreads();
  }

  if (EPI == E_ROPE) {
    unsigned short* O = (unsigned short*)out;
#pragma unroll
    for (int m = 0; m < 4; ++m) {
      const int row0 = bm0 + 64 * wr + 16 * m + 4 * l4;
#pragma unroll
      for (int n = 0; n < 2; ++n) {
        const int d = 16 * n + l15;            // 0..31
        const int col1 = bn0 + 64 * wc + d;
        const float b1 = bias[col1], b2 = bias[col1 + 32];
#pragma unroll
        for (int i = 0; i < 4; ++i) {
          const int row = row0 + i;
          const int s = row & (SS - 1);
          const float c = tc[s * 32 + d], sn = ts[s * 32 + d];
          const float x1 = acc[m][n][i] + b1;
          const float x2 = acc[m][n + 2][i] + b2;
          O[(size_t)row * 1024 + col1]      = f2bf((x1 * c - x2 * sn) * scale);
          O[(size_t)row * 1024 + col1 + 32] = f2bf((x1 * sn + x2 * c) * scale);
        }
      }
    }
  } else if (EPI == E_VT) {
    // write V transposed: vT[b][h][d][s], bf16
    unsigned short* O = (unsigned short*)out;
    const int hh = (bn0 + 64 * wc) >> 6;
#pragma unroll
    for (int m = 0; m < 4; ++m) {
      const int row0 = bm0 + 64 * wr + 16 * m + 4 * l4;
      const int b_ = row0 >> 11;
      const int s0 = row0 & (SS - 1);
#pragma unroll
      for (int n = 0; n < 4; ++n) {
        const int d = 16 * n + l15;
        const float bb = bias[bn0 + 64 * wc + d];
        ushort4 o;
        o.x = f2bf(acc[m][n][0] + bb);
        o.y = f2bf(acc[m][n][1] + bb);
        o.z = f2bf(acc[m][n][2] + bb);
        o.w = f2bf(acc[m][n][3] + bb);
        *(ushort4*)&O[((size_t)(b_ * HH + hh) * 64 + d) * SS + s0] = o;
      }
    }
  } else {
    float* O = (float*)out;
#pragma unroll
    for (int m = 0; m < 4; ++m) {
      const int row0 = bm0 + 64 * wr + 16 * m + 4 * l4;
#pragma unroll
      for (int n = 0; n < 4; ++n) {
        const int col = bn0 + 64 * wc + 16 * n + l15;
        const float bb = bias[col];
#pragma unroll
        for (int i = 0; i < 4; ++i)
          O[(size_t)(row0 + i) * 1024 + col] = acc[m][n][i] + bb;
      }
    }
  }
}

// ---------------- causal flash attention -----------------------------
// grid: 64 bh x 16 pairs. Block handles q-tiles {p, 31-p} (33 k-tiles total:
// triangle-balanced). 4 waves, wave wv owns q rows [16wv,16wv+16) of each tile.
// Double-buffered K/V staging, one barrier per k-tile, prefetch overlaps
// compute. q pre-scaled by 0.125*log2e in its RoPE epilogue -> exp2f softmax.
__global__ __launch_bounds__(256, 4) void k_attn(
    const unsigned short* __restrict__ qr,   // bf16 [8192][1024] (token major)
    const unsigned short* __restrict__ kr,   // bf16 [8192][1024]
    const unsigned short* __restrict__ vT,   // bf16 [64 bh][64 d][2048 s]
    unsigned short* __restrict__ ao)         // bf16 [8192][1024]
{
  __shared__ unsigned short Ks[2][64*64];
  __shared__ unsigned short Vs[2][64*64];
  __shared__ unsigned short Ps[4][16*64];
  const int tid = threadIdx.x, lane = tid & 63, wv = tid >> 6;
  const int l15 = lane & 15, l4 = lane >> 4;
  const int pair = blockIdx.x & 15;
  const int bh = blockIdx.x >> 4;
  const int b_ = bh >> 4, h_ = bh & 15;

  const int srow = lane >> 3;
  const int scol = ((lane & 7) ^ srow) * 8;

  const f32x4 fz = {0.f, 0.f, 0.f, 0.f};

  for (int half = 0; half < 2; ++half) {
    const int j = half ? (31 - pair) : pair;   // q-tile index, 0..31
    const int q0 = j * 64;

    const size_t qoff = ((size_t)(b_ * SS + q0 + 16 * wv + l15)) * 1024 + h_ * 64 + l4 * 8;
    const bf16x8 aq0 = ld_bf16x8(&qr[qoff]);
    const bf16x8 aq1 = ld_bf16x8(&qr[qoff + 32]);

    f32x4 accO[4];
#pragma unroll
    for (int dt = 0; dt < 4; ++dt) accO[dt] = fz;
    float mrun[4], lrun[4];
#pragma unroll
    for (int i = 0; i < 4; ++i) { mrun[i] = -1e30f; lrun[i] = 0.f; }

    // prologue: stage k-tile 0 into buffer 0
    {
      const int k0 = 0;
#pragma unroll
      for (int i = 0; i < 2; ++i) {
        const int c = wv * 2 + i;
        const int row = c * 8 + srow;
        gload_lds16(kr + ((size_t)(b_ * SS + k0 + row)) * 1024 + h_ * 64 + scol,
                    (char*)&Ks[0][0] + c * 1024);
        gload_lds16(vT + ((size_t)(bh * 64 + row)) * SS + k0 + scol,
                    (char*)&Vs[0][0] + c * 1024);
      }
    }
    __syncthreads();

    int cur = 0;
    for (int kt = 0; kt <= j; ++kt) {
      // prefetch next k-tile into the other buffer (overlaps compute below)
      if (kt < j) {
        const int k0 = (kt + 1) * 64;
        const int nb = cur ^ 1;
#pragma unroll
        for (int i = 0; i < 2; ++i) {
          const int c = wv * 2 + i;
          const int row = c * 8 + srow;
          gload_lds16(kr + ((size_t)(b_ * SS + k0 + row)) * 1024 + h_ * 64 + scol,
                      (char*)&Ks[nb][0] + c * 1024);
          gload_lds16(vT + ((size_t)(bh * 64 + row)) * SS + k0 + scol,
                      (char*)&Vs[nb][0] + c * 1024);
        }
      }

      const bool diag = (kt == j);
      f32x4 sc[4];
#pragma unroll
      for (int n = 0; n < 4; ++n) {
        if (!diag || n <= wv) {
          const int row = 16 * n + l15;
          const int sl0 = ((l4 + 0) ^ (l15 & 7)) * 8;
          const int sl1 = ((l4 + 4) ^ (l15 & 7)) * 8;
          bf16x8 kf0 = ld_bf16x8(&Ks[cur][row * 64 + sl0]);
          bf16x8 kf1 = ld_bf16x8(&Ks[cur][row * 64 + sl1]);
          sc[n] = __builtin_amdgcn_mfma_f32_16x16x32_bf16(aq0, kf0, fz, 0, 0, 0);
          sc[n] = __builtin_amdgcn_mfma_f32_16x16x32_bf16(aq1, kf1, sc[n], 0, 0, 0);
        } else {
          sc[n] = fz;   // fully-masked sub-tile; mask below sets -1e30
        }
      }
      if (diag) {
#pragma unroll
        for (int n = 0; n < 4; ++n)
#pragma unroll
          for (int i = 0; i < 4; ++i) {
            const int kj = 16 * n + l15;
            const int qi = 16 * wv + 4 * l4 + i;
            if (kj > qi) sc[n][i] = -1e30f;
          }
      }

      // tile row-max (per lane: rows 4*l4+i)
      float tmax[4];
#pragma unroll
      for (int i = 0; i < 4; ++i) {
        float t = fmaxf(fmaxf(sc[0][i], sc[1][i]), fmaxf(sc[2][i], sc[3][i]));
        t = fmaxf(t, __shfl_xor(t, 1));
        t = fmaxf(t, __shfl_xor(t, 2));
        t = fmaxf(t, __shfl_xor(t, 4));
        t = fmaxf(t, __shfl_xor(t, 8));
        tmax[i] = t;
      }
      // defer-max: only rescale when some row's max grew (wave-uniform branch)
      bool grow = (tmax[0] > mrun[0]) | (tmax[1] > mrun[1]) |
                  (tmax[2] > mrun[2]) | (tmax[3] > mrun[3]);
      if (__any(grow)) {
#pragma unroll
        for (int i = 0; i < 4; ++i) {
          const float mn = fmaxf(mrun[i], tmax[i]);
          const float alpha = exp2f(mrun[i] - mn);
          mrun[i] = mn;
          lrun[i] *= alpha;
#pragma unroll
          for (int dt = 0; dt < 4; ++dt) accO[dt][i] *= alpha;
        }
      }
      float pn[4][4];
#pragma unroll
      for (int i = 0; i < 4; ++i) {
        float rs = 0.f;
#pragma unroll
        for (int n = 0; n < 4; ++n) { pn[n][i] = exp2f(sc[n][i] - mrun[i]); rs += pn[n][i]; }
        rs += __shfl_xor(rs, 1);
        rs += __shfl_xor(rs, 2);
        rs += __shfl_xor(rs, 4);
        rs += __shfl_xor(rs, 8);
        lrun[i] += rs;
      }
      // P -> bf16 -> per-wave swizzled LDS tile [16 q][64 kj]
#pragma unroll
      for (int n = 0; n < 4; ++n)
#pragma unroll
        for (int i = 0; i < 4; ++i) {
          const int r = 4 * l4 + i;
          const int cc = 16 * n + l15;
          const int phys = (cc >> 3) ^ (r & 7);
          Ps[wv][r * 64 + phys * 8 + (cc & 7)] = f2bf(pn[n][i]);
        }
#pragma unroll
      for (int kk = 0; kk < 2; ++kk) {
        if (diag && wv < 2 && kk == 1) continue;  // cols 32..63 all zero for waves 0,1
        const int psl = ((l4 + 4 * kk) ^ (l15 & 7)) * 8;
        bf16x8 pa = ld_bf16x8(&Ps[wv][l15 * 64 + psl]);
#pragma unroll
        for (int dt = 0; dt < 4; ++dt) {
          const int row = 16 * dt + l15;
          const int vsl = ((l4 + 4 * kk) ^ (l15 & 7)) * 8;
          bf16x8 vb = ld_bf16x8(&Vs[cur][row * 64 + vsl]);
          accO[dt] = __builtin_amdgcn_mfma_f32_16x16x32_bf16(pa, vb, accO[dt], 0, 0, 0);
        }
      }
      __syncthreads();   // drains prefetch (vmcnt) + protects buffer reuse
      cur ^= 1;
    }

#pragma unroll
    for (int i = 0; i < 4; ++i) {
      const float inv = 1.0f / lrun[i];
      const size_t row = (size_t)(b_ * SS + q0 + 16 * wv + 4 * l4 + i);
#pragma unroll
      for (int dt = 0; dt < 4; ++dt)
        ao[row * 1024 + h_ * 64 + 16 * dt + l15] = f2bf(accO[dt][i] * inv);
    }
  }
}

extern "C" void kernel_launch(void* const* d_in, const int* in_sizes, int n_in,
                              void* d_out, int out_size, void* d_ws, size_t ws_size,
                              hipStream_t stream) {
  const float* Q  = (const float*)d_in[0];
  const float* K  = (const float*)d_in[1];
  const float* V  = (const float*)d_in[2];
  const float* Wq = (const float*)d_in[3];
  const float* bq = (const float*)d_in[4];
  const float* Wk = (const float*)d_in[5];
  const float* bk = (const float*)d_in[6];
  const float* Wv = (const float*)d_in[7];
  const float* bv = (const float*)d_in[8];
  const float* Wo = (const float*)d_in[9];
  const float* bo = (const float*)d_in[10];
  float* out = (float*)d_out;

  char* ws = (char*)d_ws;
  float* tc = (float*)(ws);
  float* ts = (float*)(ws + 256 * 1024);
  unsigned short* wqb = (unsigned short*)(ws + 512 * 1024);
  unsigned short* wkb = wqb + (1u << 20);
  unsigned short* wvb = wkb + (1u << 20);
  unsigned short* wob = wvb + (1u << 20);
  unsigned short* xb  = wob + (1u << 20);
  unsigned short* qrb = xb  + (size_t)MTOT * 1024;
  unsigned short* krb = qrb + (size_t)MTOT * 1024;
  unsigned short* vtb = krb + (size_t)MTOT * 1024;
  unsigned short* aob = vtb + (size_t)MTOT * 1024;

  k_rope_tables<<<256, 256, 0, stream>>>(tc, ts);
  k_cvt_bf16<<<1024, 256, 0, stream>>>(Wq, wqb, 1024 * 1024 / 4);
  k_cvt_bf16<<<1024, 256, 0, stream>>>(Wk, wkb, 1024 * 1024 / 4);
  k_cvt_bf16<<<1024, 256, 0, stream>>>(Wv, wvb, 1024 * 1024 / 4);
  k_cvt_bf16<<<1024, 256, 0, stream>>>(Wo, wob, 1024 * 1024 / 4);

  dim3 gg(MTOT / 128, 8);
  const float qsc = 0.125f * 1.4426950408889634f;  // fold 1/sqrt(64) and log2e

  k_cvt_bf16<<<MTOT * 1024 / 4 / 256, 256, 0, stream>>>(Q, xb, MTOT * 1024 / 4);
  k_gemm<E_ROPE><<<gg, 256, 0, stream>>>(xb, wqb, bq, qrb, tc, ts, qsc);
  k_cvt_bf16<<<MTOT * 1024 / 4 / 256, 256, 0, stream>>>(K, xb, MTOT * 1024 / 4);
  k_gemm<E_ROPE><<<gg, 256, 0, stream>>>(xb, wkb, bk, krb, tc, ts, 1.0f);
  k_cvt_bf16<<<MTOT * 1024 / 4 / 256, 256, 0, stream>>>(V, xb, MTOT * 1024 / 4);
  k_gemm<E_VT><<<gg, 256, 0, stream>>>(xb, wvb, bv, vtb, tc, ts, 1.0f);

  k_attn<<<64 * 16, 256, 0, stream>>>(qrb, krb, vtb, aob);

  k_gemm<E_F32><<<gg, 256, 0, stream>>>(aob, wob, bo, out, tc, ts, 1.0f);
}

// Round 5
// 378.706 us; speedup vs baseline: 1.3369x; 1.0303x over previous
//
#include <hip/hip_runtime.h>
#include <hip/hip_bf16.h>

#define BB 4
#define SS 2048
#define DDIM 1024
#define HH 16
#define MTOT (BB*SS)   // 8192

typedef __attribute__((ext_vector_type(8))) __bf16 bf16x8;
typedef __attribute__((ext_vector_type(4))) float f32x4;

static __device__ __forceinline__ unsigned short f2bf(float f) {
  union { float f; unsigned u; } v; v.f = f;
  unsigned r = v.u + 0x7FFFu + ((v.u >> 16) & 1u);
  return (unsigned short)(r >> 16);
}

// alias-safe 16B load (ds_read_b128 / global_load_dwordx4)
static __device__ __forceinline__ bf16x8 ld_bf16x8(const void* p) {
  bf16x8 r;
  __builtin_memcpy(&r, p, 16);
  return r;
}

static __device__ __forceinline__ void gload_lds16(const void* g, void* l) {
  __builtin_amdgcn_global_load_lds(
      (const __attribute__((address_space(1))) unsigned int*)g,
      (__attribute__((address_space(3))) unsigned int*)l, 16, 0, 0);
}

// ---------------- RoPE tables: interleaved (cos,sin) [2048][32] ----------------
__global__ void k_rope_tables(float2* __restrict__ t) {
  int i = blockIdx.x * 256 + threadIdx.x;   // 65536 total
  int s = i >> 5, d = i & 31;
  float inv = powf(10000.0f, -((float)d) / 32.0f);
  float a = (float)s * inv;
  t[i] = make_float2(cosf(a), sinf(a));
}

// ---------------- fp32 -> bf16 convert, 4 elems/thread ----------------
__global__ void k_cvt_bf16(const float* __restrict__ in,
                           unsigned short* __restrict__ out, int n4) {
  int i = blockIdx.x * 256 + threadIdx.x;
  if (i >= n4) return;
  float4 v = ((const float4*)in)[i];
  ushort4 o;
  o.x = f2bf(v.x); o.y = f2bf(v.y); o.z = f2bf(v.z); o.w = f2bf(v.w);
  ((ushort4*)out)[i] = o;
}

// ---------------- GEMM: C[M][1024] = A[M][1024] * Bw[1024][1024]^T + bias ----
// 128x128 tile, BK=64, 4 waves (each 64x64), XOR-swizzled LDS (T2),
// global_load_lds width-16 staging with pre-swizzled global source.
#define E_ROPE 0
#define E_VT   1
#define E_F32  2

template<int EPI>
__global__ __launch_bounds__(256, 3) void k_gemm(
    const unsigned short* __restrict__ A,    // bf16 [M][1024]
    const unsigned short* __restrict__ Bw,   // bf16 [1024][1024] (row n, k contig)
    const float* __restrict__ bias,          // [1024]
    void* __restrict__ out,
    const float2* __restrict__ tcs,
    float scale)
{
  __shared__ unsigned short As[128*64];
  __shared__ unsigned short Bs[128*64];
  const int tid  = threadIdx.x;
  const int lane = tid & 63;
  const int wv   = tid >> 6;
  const int wr   = wv >> 1, wc = wv & 1;
  const int l15  = lane & 15, l4 = lane >> 4;
  const int bm0  = blockIdx.x * 128;
  const int bn0  = blockIdx.y * 128;

  const f32x4 fz = {0.f, 0.f, 0.f, 0.f};
  f32x4 acc[4][4];
#pragma unroll
  for (int m = 0; m < 4; ++m)
#pragma unroll
    for (int n = 0; n < 4; ++n) acc[m][n] = fz;

  // staging geometry: chunk c = wv*4+i covers rows c*8..c*8+7 (1KB linear LDS)
  const int srow = lane >> 3;            // 0..7 within chunk
  const int scol = ((lane & 7) ^ srow) * 8;  // pre-swizzled source column (shorts)

  for (int kt = 0; kt < 16; ++kt) {
    const int k0 = kt * 64;
#pragma unroll
    for (int i = 0; i < 4; ++i) {
      const int c = wv * 4 + i;
      const int row = c * 8 + srow;
      gload_lds16(A  + (size_t)(bm0 + row) * 1024 + k0 + scol, (char*)As + c * 1024);
      gload_lds16(Bw + (size_t)(bn0 + row) * 1024 + k0 + scol, (char*)Bs + c * 1024);
    }
    __syncthreads();
#pragma unroll
    for (int h = 0; h < 2; ++h) {
      bf16x8 af[4], bfr[4];
#pragma unroll
      for (int m = 0; m < 4; ++m) {
        const int row = 64 * wr + 16 * m + l15;
        const int sl = ((l4 + 4 * h) ^ (l15 & 7)) * 8;
        af[m] = ld_bf16x8(&As[row * 64 + sl]);
      }
#pragma unroll
      for (int n = 0; n < 4; ++n) {
        const int row = 64 * wc + 16 * n + l15;
        const int sl = ((l4 + 4 * h) ^ (l15 & 7)) * 8;
        bfr[n] = ld_bf16x8(&Bs[row * 64 + sl]);
      }
#pragma unroll
      for (int m = 0; m < 4; ++m)
#pragma unroll
        for (int n = 0; n < 4; ++n)
          acc[m][n] = __builtin_amdgcn_mfma_f32_16x16x32_bf16(af[m], bfr[n], acc[m][n], 0, 0, 0);
    }
    __syncthreads();
  }

  if (EPI == E_ROPE) {
    unsigned short* O = (unsigned short*)out;
#pragma unroll
    for (int m = 0; m < 4; ++m) {
      const int row0 = bm0 + 64 * wr + 16 * m + 4 * l4;
#pragma unroll
      for (int n = 0; n < 2; ++n) {
        const int d = 16 * n + l15;            // 0..31
        const int col1 = bn0 + 64 * wc + d;
        const float b1 = bias[col1], b2 = bias[col1 + 32];
#pragma unroll
        for (int i = 0; i < 4; ++i) {
          const int row = row0 + i;
          const int s = row & (SS - 1);
          const float2 cs = tcs[s * 32 + d];
          const float x1 = acc[m][n][i] + b1;
          const float x2 = acc[m][n + 2][i] + b2;
          O[(size_t)row * 1024 + col1]      = f2bf((x1 * cs.x - x2 * cs.y) * scale);
          O[(size_t)row * 1024 + col1 + 32] = f2bf((x1 * cs.y + x2 * cs.x) * scale);
        }
      }
    }
  } else if (EPI == E_VT) {
    // write V transposed: vT[b][h][d][s], bf16
    unsigned short* O = (unsigned short*)out;
    const int hh = (bn0 + 64 * wc) >> 6;
#pragma unroll
    for (int m = 0; m < 4; ++m) {
      const int row0 = bm0 + 64 * wr + 16 * m + 4 * l4;
      const int b_ = row0 >> 11;
      const int s0 = row0 & (SS - 1);
#pragma unroll
      for (int n = 0; n < 4; ++n) {
        const int d = 16 * n + l15;
        const float bb = bias[bn0 + 64 * wc + d];
        ushort4 o;
        o.x = f2bf(acc[m][n][0] + bb);
        o.y = f2bf(acc[m][n][1] + bb);
        o.z = f2bf(acc[m][n][2] + bb);
        o.w = f2bf(acc[m][n][3] + bb);
        *(ushort4*)&O[((size_t)(b_ * HH + hh) * 64 + d) * SS + s0] = o;
      }
    }
  } else {
    float* O = (float*)out;
#pragma unroll
    for (int m = 0; m < 4; ++m) {
      const int row0 = bm0 + 64 * wr + 16 * m + 4 * l4;
#pragma unroll
      for (int n = 0; n < 4; ++n) {
        const int col = bn0 + 64 * wc + 16 * n + l15;
        const float bb = bias[col];
#pragma unroll
        for (int i = 0; i < 4; ++i)
          O[(size_t)(row0 + i) * 1024 + col] = acc[m][n][i] + bb;
      }
    }
  }
}

// ---------------- causal flash attention -----------------------------
// grid: 1024 blocks, bh = blockIdx&63 (fast index -> same-bh blocks land on
// the same XCD under round-robin dispatch -> K/V stay in one L2). Block does
// q-tiles {p, 31-p} (33 k-tiles: triangle-balanced). 4 waves, wave wv owns
// q rows [16wv,16wv+16). Double-buffered K/V, one barrier per k-tile.
// q pre-scaled by 0.125*log2e -> exp2f softmax. Defer-max THR=11 (log2).
__global__ __launch_bounds__(256, 4) void k_attn(
    const unsigned short* __restrict__ qr,   // bf16 [8192][1024] (token major)
    const unsigned short* __restrict__ kr,   // bf16 [8192][1024]
    const unsigned short* __restrict__ vT,   // bf16 [64 bh][64 d][2048 s]
    unsigned short* __restrict__ ao)         // bf16 [8192][1024]
{
  __shared__ unsigned short Ks[2][64*64];
  __shared__ unsigned short Vs[2][64*64];
  __shared__ unsigned short Ps[4][16*64];
  const int tid = threadIdx.x, lane = tid & 63, wv = tid >> 6;
  const int l15 = lane & 15, l4 = lane >> 4;
  const int bh = blockIdx.x & 63;            // fast index: XCD locality for K/V
  const int pair = blockIdx.x >> 6;
  const int b_ = bh >> 4, h_ = bh & 15;

  const int srow = lane >> 3;
  const int scol = ((lane & 7) ^ srow) * 8;

  const f32x4 fz = {0.f, 0.f, 0.f, 0.f};

  for (int half = 0; half < 2; ++half) {
    const int j = half ? (31 - pair) : pair;   // q-tile index, 0..31
    const int q0 = j * 64;

    const size_t qoff = ((size_t)(b_ * SS + q0 + 16 * wv + l15)) * 1024 + h_ * 64 + l4 * 8;
    const bf16x8 aq0 = ld_bf16x8(&qr[qoff]);
    const bf16x8 aq1 = ld_bf16x8(&qr[qoff + 32]);

    f32x4 accO[4];
#pragma unroll
    for (int dt = 0; dt < 4; ++dt) accO[dt] = fz;
    float mrun[4], lrun[4];
#pragma unroll
    for (int i = 0; i < 4; ++i) { mrun[i] = -1e30f; lrun[i] = 0.f; }

    // prologue: stage k-tile 0 into buffer 0
    {
#pragma unroll
      for (int i = 0; i < 2; ++i) {
        const int c = wv * 2 + i;
        const int row = c * 8 + srow;
        gload_lds16(kr + ((size_t)(b_ * SS + row)) * 1024 + h_ * 64 + scol,
                    (char*)&Ks[0][0] + c * 1024);
        gload_lds16(vT + ((size_t)(bh * 64 + row)) * SS + scol,
                    (char*)&Vs[0][0] + c * 1024);
      }
    }
    __syncthreads();

    int cur = 0;
    for (int kt = 0; kt <= j; ++kt) {
      // prefetch next k-tile into the other buffer (overlaps compute below)
      if (kt < j) {
        const int k0 = (kt + 1) * 64;
        const int nb = cur ^ 1;
#pragma unroll
        for (int i = 0; i < 2; ++i) {
          const int c = wv * 2 + i;
          const int row = c * 8 + srow;
          gload_lds16(kr + ((size_t)(b_ * SS + k0 + row)) * 1024 + h_ * 64 + scol,
                      (char*)&Ks[nb][0] + c * 1024);
          gload_lds16(vT + ((size_t)(bh * 64 + row)) * SS + k0 + scol,
                      (char*)&Vs[nb][0] + c * 1024);
        }
      }

      const bool diag = (kt == j);
      f32x4 sc[4];
      __builtin_amdgcn_s_setprio(1);
#pragma unroll
      for (int n = 0; n < 4; ++n) {
        if (!diag || n <= wv) {
          const int row = 16 * n + l15;
          const int sl0 = ((l4 + 0) ^ (l15 & 7)) * 8;
          const int sl1 = ((l4 + 4) ^ (l15 & 7)) * 8;
          bf16x8 kf0 = ld_bf16x8(&Ks[cur][row * 64 + sl0]);
          bf16x8 kf1 = ld_bf16x8(&Ks[cur][row * 64 + sl1]);
          sc[n] = __builtin_amdgcn_mfma_f32_16x16x32_bf16(aq0, kf0, fz, 0, 0, 0);
          sc[n] = __builtin_amdgcn_mfma_f32_16x16x32_bf16(aq1, kf1, sc[n], 0, 0, 0);
        } else {
          sc[n] = fz;   // fully-masked sub-tile; mask below sets -1e30
        }
      }
      __builtin_amdgcn_s_setprio(0);
      if (diag) {
#pragma unroll
        for (int n = 0; n < 4; ++n)
#pragma unroll
          for (int i = 0; i < 4; ++i) {
            const int kj = 16 * n + l15;
            const int qi = 16 * wv + 4 * l4 + i;
            if (kj > qi) sc[n][i] = -1e30f;
          }
      }

      // tile row-max (per lane: rows 4*l4+i)
      float tmax[4];
#pragma unroll
      for (int i = 0; i < 4; ++i) {
        float t = fmaxf(fmaxf(fmaxf(sc[0][i], sc[1][i]), sc[2][i]), sc[3][i]);
        t = fmaxf(t, __shfl_xor(t, 1));
        t = fmaxf(t, __shfl_xor(t, 2));
        t = fmaxf(t, __shfl_xor(t, 4));
        t = fmaxf(t, __shfl_xor(t, 8));
        tmax[i] = t;
      }
      // defer-max (T13): rescale only when some row grew by > 11 log2-units
      // (P then bounded by 2^11 = 2048 -- fine in bf16/f32 accum)
      bool need = (tmax[0] > mrun[0] + 11.f) | (tmax[1] > mrun[1] + 11.f) |
                  (tmax[2] > mrun[2] + 11.f) | (tmax[3] > mrun[3] + 11.f);
      if (__any(need)) {
#pragma unroll
        for (int i = 0; i < 4; ++i) {
          const float mn = fmaxf(mrun[i], tmax[i]);
          const float alpha = exp2f(mrun[i] - mn);
          mrun[i] = mn;
          lrun[i] *= alpha;
#pragma unroll
          for (int dt = 0; dt < 4; ++dt) accO[dt][i] *= alpha;
        }
      }
      float pn[4][4];
#pragma unroll
      for (int i = 0; i < 4; ++i) {
        float rs = 0.f;
#pragma unroll
        for (int n = 0; n < 4; ++n) { pn[n][i] = exp2f(sc[n][i] - mrun[i]); rs += pn[n][i]; }
        rs += __shfl_xor(rs, 1);
        rs += __shfl_xor(rs, 2);
        rs += __shfl_xor(rs, 4);
        rs += __shfl_xor(rs, 8);
        lrun[i] += rs;
      }
      // P -> bf16 -> per-wave swizzled LDS tile [16 q][64 kj]
#pragma unroll
      for (int n = 0; n < 4; ++n)
#pragma unroll
        for (int i = 0; i < 4; ++i) {
          const int r = 4 * l4 + i;
          const int cc = 16 * n + l15;
          const int phys = (cc >> 3) ^ (r & 7);
          Ps[wv][r * 64 + phys * 8 + (cc & 7)] = f2bf(pn[n][i]);
        }
      __builtin_amdgcn_s_setprio(1);
#pragma unroll
      for (int kk = 0; kk < 2; ++kk) {
        if (diag && wv < 2 && kk == 1) continue;  // cols 32..63 all zero for waves 0,1
        const int psl = ((l4 + 4 * kk) ^ (l15 & 7)) * 8;
        bf16x8 pa = ld_bf16x8(&Ps[wv][l15 * 64 + psl]);
#pragma unroll
        for (int dt = 0; dt < 4; ++dt) {
          const int row = 16 * dt + l15;
          const int vsl = ((l4 + 4 * kk) ^ (l15 & 7)) * 8;
          bf16x8 vb = ld_bf16x8(&Vs[cur][row * 64 + vsl]);
          accO[dt] = __builtin_amdgcn_mfma_f32_16x16x32_bf16(pa, vb, accO[dt], 0, 0, 0);
        }
      }
      __builtin_amdgcn_s_setprio(0);
      __syncthreads();   // drains prefetch (vmcnt) + protects buffer reuse
      cur ^= 1;
    }

#pragma unroll
    for (int i = 0; i < 4; ++i) {
      const float inv = 1.0f / lrun[i];
      const size_t row = (size_t)(b_ * SS + q0 + 16 * wv + 4 * l4 + i);
#pragma unroll
      for (int dt = 0; dt < 4; ++dt)
        ao[row * 1024 + h_ * 64 + 16 * dt + l15] = f2bf(accO[dt][i] * inv);
    }
  }
}

extern "C" void kernel_launch(void* const* d_in, const int* in_sizes, int n_in,
                              void* d_out, int out_size, void* d_ws, size_t ws_size,
                              hipStream_t stream) {
  const float* Q  = (const float*)d_in[0];
  const float* K  = (const float*)d_in[1];
  const float* V  = (const float*)d_in[2];
  const float* Wq = (const float*)d_in[3];
  const float* bq = (const float*)d_in[4];
  const float* Wk = (const float*)d_in[5];
  const float* bk = (const float*)d_in[6];
  const float* Wv = (const float*)d_in[7];
  const float* bv = (const float*)d_in[8];
  const float* Wo = (const float*)d_in[9];
  const float* bo = (const float*)d_in[10];
  float* out = (float*)d_out;

  char* ws = (char*)d_ws;
  float2* tcs = (float2*)(ws);               // 512 KB interleaved cos/sin
  unsigned short* wqb = (unsigned short*)(ws + 512 * 1024);
  unsigned short* wkb = wqb + (1u << 20);
  unsigned short* wvb = wkb + (1u << 20);
  unsigned short* wob = wvb + (1u << 20);
  unsigned short* xb  = wob + (1u << 20);
  unsigned short* qrb = xb  + (size_t)MTOT * 1024;
  unsigned short* krb = qrb + (size_t)MTOT * 1024;
  unsigned short* vtb = krb + (size_t)MTOT * 1024;
  unsigned short* aob = vtb + (size_t)MTOT * 1024;

  k_rope_tables<<<256, 256, 0, stream>>>(tcs);
  k_cvt_bf16<<<1024, 256, 0, stream>>>(Wq, wqb, 1024 * 1024 / 4);
  k_cvt_bf16<<<1024, 256, 0, stream>>>(Wk, wkb, 1024 * 1024 / 4);
  k_cvt_bf16<<<1024, 256, 0, stream>>>(Wv, wvb, 1024 * 1024 / 4);
  k_cvt_bf16<<<1024, 256, 0, stream>>>(Wo, wob, 1024 * 1024 / 4);

  dim3 gg(MTOT / 128, 8);
  const float qsc = 0.125f * 1.4426950408889634f;  // fold 1/sqrt(64) and log2e

  k_cvt_bf16<<<MTOT * 1024 / 4 / 256, 256, 0, stream>>>(Q, xb, MTOT * 1024 / 4);
  k_gemm<E_ROPE><<<gg, 256, 0, stream>>>(xb, wqb, bq, qrb, tcs, qsc);
  k_cvt_bf16<<<MTOT * 1024 / 4 / 256, 256, 0, stream>>>(K, xb, MTOT * 1024 / 4);
  k_gemm<E_ROPE><<<gg, 256, 0, stream>>>(xb, wkb, bk, krb, tcs, 1.0f);
  k_cvt_bf16<<<MTOT * 1024 / 4 / 256, 256, 0, stream>>>(V, xb, MTOT * 1024 / 4);
  k_gemm<E_VT><<<gg, 256, 0, stream>>>(xb, wvb, bv, vtb, tcs, 1.0f);

  k_attn<<<64 * 16, 256, 0, stream>>>(qrb, krb, vtb, aob);

  k_gemm<E_F32><<<gg, 256, 0, stream>>>(aob, wob, bo, out, tcs, 1.0f);
}

// Round 7
// 341.692 us; speedup vs baseline: 1.4817x; 1.1083x over previous
//
#include <hip/hip_runtime.h>
#include <hip/hip_bf16.h>

#define BB 4
#define SS 2048
#define DDIM 1024
#define HH 16
#define MTOT (BB*SS)   // 8192

typedef __attribute__((ext_vector_type(8))) __bf16 bf16x8;
typedef __attribute__((ext_vector_type(4))) float f32x4;

static __device__ __forceinline__ unsigned short f2bf(float f) {
  union { float f; unsigned u; } v; v.f = f;
  unsigned r = v.u + 0x7FFFu + ((v.u >> 16) & 1u);
  return (unsigned short)(r >> 16);
}

// alias-safe 16B load (ds_read_b128 / global_load_dwordx4)
static __device__ __forceinline__ bf16x8 ld_bf16x8(const void* p) {
  bf16x8 r;
  __builtin_memcpy(&r, p, 16);
  return r;
}

static __device__ __forceinline__ void gload_lds16(const void* g, void* l) {
  __builtin_amdgcn_global_load_lds(
      (const __attribute__((address_space(1))) unsigned int*)g,
      (__attribute__((address_space(3))) unsigned int*)l, 16, 0, 0);
}

// ---------------- RoPE tables: interleaved (cos,sin) [2048][32] ----------------
__global__ void k_rope_tables(float2* __restrict__ t) {
  int i = blockIdx.x * 256 + threadIdx.x;   // 65536 total
  int s = i >> 5, d = i & 31;
  float inv = powf(10000.0f, -((float)d) / 32.0f);
  float a = (float)s * inv;
  t[i] = make_float2(cosf(a), sinf(a));
}

// ---------------- fp32 -> bf16 convert, 4 elems/thread ----------------
__global__ void k_cvt_bf16(const float* __restrict__ in,
                           unsigned short* __restrict__ out, int n4) {
  int i = blockIdx.x * 256 + threadIdx.x;
  if (i >= n4) return;
  float4 v = ((const float4*)in)[i];
  ushort4 o;
  o.x = f2bf(v.x); o.y = f2bf(v.y); o.z = f2bf(v.z); o.w = f2bf(v.w);
  ((ushort4*)out)[i] = o;
}

// ---------------- GEMM: C[M][1024] = A[M][1024] * Bw[1024][1024]^T + bias ----
// 128x128 tile, BK=64, 4 waves (each 64x64), XOR-swizzled LDS (T2),
// global_load_lds width-16 staging with pre-swizzled global source.
#define E_ROPE 0
#define E_VT   1
#define E_F32  2

template<int EPI>
__global__ __launch_bounds__(256, 3) void k_gemm(
    const unsigned short* __restrict__ A,    // bf16 [M][1024]
    const unsigned short* __restrict__ Bw,   // bf16 [1024][1024] (row n, k contig)
    const float* __restrict__ bias,          // [1024]
    void* __restrict__ out,
    const float2* __restrict__ tcs,
    float scale)
{
  __shared__ unsigned short As[128*64];
  __shared__ unsigned short Bs[128*64];
  const int tid  = threadIdx.x;
  const int lane = tid & 63;
  const int wv   = tid >> 6;
  const int wr   = wv >> 1, wc = wv & 1;
  const int l15  = lane & 15, l4 = lane >> 4;
  const int bm0  = blockIdx.x * 128;
  const int bn0  = blockIdx.y * 128;

  const f32x4 fz = {0.f, 0.f, 0.f, 0.f};
  f32x4 acc[4][4];
#pragma unroll
  for (int m = 0; m < 4; ++m)
#pragma unroll
    for (int n = 0; n < 4; ++n) acc[m][n] = fz;

  // staging geometry: chunk c = wv*4+i covers rows c*8..c*8+7 (1KB linear LDS)
  const int srow = lane >> 3;            // 0..7 within chunk
  const int scol = ((lane & 7) ^ srow) * 8;  // pre-swizzled source column (shorts)

  for (int kt = 0; kt < 16; ++kt) {
    const int k0 = kt * 64;
#pragma unroll
    for (int i = 0; i < 4; ++i) {
      const int c = wv * 4 + i;
      const int row = c * 8 + srow;
      gload_lds16(A  + (size_t)(bm0 + row) * 1024 + k0 + scol, (char*)As + c * 1024);
      gload_lds16(Bw + (size_t)(bn0 + row) * 1024 + k0 + scol, (char*)Bs + c * 1024);
    }
    __syncthreads();
#pragma unroll
    for (int h = 0; h < 2; ++h) {
      bf16x8 af[4], bfr[4];
#pragma unroll
      for (int m = 0; m < 4; ++m) {
        const int row = 64 * wr + 16 * m + l15;
        const int sl = ((l4 + 4 * h) ^ (l15 & 7)) * 8;
        af[m] = ld_bf16x8(&As[row * 64 + sl]);
      }
#pragma unroll
      for (int n = 0; n < 4; ++n) {
        const int row = 64 * wc + 16 * n + l15;
        const int sl = ((l4 + 4 * h) ^ (l15 & 7)) * 8;
        bfr[n] = ld_bf16x8(&Bs[row * 64 + sl]);
      }
#pragma unroll
      for (int m = 0; m < 4; ++m)
#pragma unroll
        for (int n = 0; n < 4; ++n)
          acc[m][n] = __builtin_amdgcn_mfma_f32_16x16x32_bf16(af[m], bfr[n], acc[m][n], 0, 0, 0);
    }
    __syncthreads();
  }

  if (EPI == E_ROPE) {
    unsigned short* O = (unsigned short*)out;
#pragma unroll
    for (int m = 0; m < 4; ++m) {
      const int row0 = bm0 + 64 * wr + 16 * m + 4 * l4;
#pragma unroll
      for (int n = 0; n < 2; ++n) {
        const int d = 16 * n + l15;            // 0..31
        const int col1 = bn0 + 64 * wc + d;
        const float b1 = bias[col1], b2 = bias[col1 + 32];
#pragma unroll
        for (int i = 0; i < 4; ++i) {
          const int row = row0 + i;
          const int s = row & (SS - 1);
          const float2 cs = tcs[s * 32 + d];
          const float x1 = acc[m][n][i] + b1;
          const float x2 = acc[m][n + 2][i] + b2;
          O[(size_t)row * 1024 + col1]      = f2bf((x1 * cs.x - x2 * cs.y) * scale);
          O[(size_t)row * 1024 + col1 + 32] = f2bf((x1 * cs.y + x2 * cs.x) * scale);
        }
      }
    }
  } else if (EPI == E_VT) {
    // write V transposed: vT[b][h][d][s], bf16
    unsigned short* O = (unsigned short*)out;
    const int hh = (bn0 + 64 * wc) >> 6;
#pragma unroll
    for (int m = 0; m < 4; ++m) {
      const int row0 = bm0 + 64 * wr + 16 * m + 4 * l4;
      const int b_ = row0 >> 11;
      const int s0 = row0 & (SS - 1);
#pragma unroll
      for (int n = 0; n < 4; ++n) {
        const int d = 16 * n + l15;
        const float bb = bias[bn0 + 64 * wc + d];
        ushort4 o;
        o.x = f2bf(acc[m][n][0] + bb);
        o.y = f2bf(acc[m][n][1] + bb);
        o.z = f2bf(acc[m][n][2] + bb);
        o.w = f2bf(acc[m][n][3] + bb);
        *(ushort4*)&O[((size_t)(b_ * HH + hh) * 64 + d) * SS + s0] = o;
      }
    }
  } else {
    float* O = (float*)out;
#pragma unroll
    for (int m = 0; m < 4; ++m) {
      const int row0 = bm0 + 64 * wr + 16 * m + 4 * l4;
#pragma unroll
      for (int n = 0; n < 4; ++n) {
        const int col = bn0 + 64 * wc + 16 * n + l15;
        const float bb = bias[col];
#pragma unroll
        for (int i = 0; i < 4; ++i)
          O[(size_t)(row0 + i) * 1024 + col] = acc[m][n][i] + bb;
      }
    }
  }
}

// ---------------- causal flash attention -----------------------------
// grid: 1024 blocks, bh = blockIdx&63 (XCD L2 locality). Block does q-tiles
// {p, 31-p} (33 k-tiles: triangle-balanced). 4 waves, wave wv owns q rows
// [16wv,16wv+16). Double-buffered K/V, one barrier per k-tile.
// Softmax: wave-global running max (valid: mrun is just a per-row-consistent
// offset; defer-max bound sc-mrun<=11 still holds), row sums via all-ones
// MFMA accumulator (D[q][*] = sum_k P[q,k], same reg layout as accO).
// q pre-scaled by 0.125*log2e -> exp2f softmax.
__global__ __launch_bounds__(256, 4) void k_attn(
    const unsigned short* __restrict__ qr,   // bf16 [8192][1024] (token major)
    const unsigned short* __restrict__ kr,   // bf16 [8192][1024]
    const unsigned short* __restrict__ vT,   // bf16 [64 bh][64 d][2048 s]
    unsigned short* __restrict__ ao)         // bf16 [8192][1024]
{
  __shared__ unsigned short Ks[2][64*64];
  __shared__ unsigned short Vs[2][64*64];
  __shared__ unsigned short Ps[4][16*64];
  const int tid = threadIdx.x, lane = tid & 63, wv = tid >> 6;
  const int l15 = lane & 15, l4 = lane >> 4;
  const int bh = blockIdx.x & 63;            // fast index: XCD locality for K/V
  const int pair = blockIdx.x >> 6;
  const int b_ = bh >> 4, h_ = bh & 15;

  const int srow = lane >> 3;
  const int scol = ((lane & 7) ^ srow) * 8;

  const f32x4 fz = {0.f, 0.f, 0.f, 0.f};
  bf16x8 ones;
#pragma unroll
  for (int j = 0; j < 8; ++j) ones[j] = (__bf16)1.0f;

  for (int half = 0; half < 2; ++half) {
    const int j = half ? (31 - pair) : pair;   // q-tile index, 0..31
    const int q0 = j * 64;

    const size_t qoff = ((size_t)(b_ * SS + q0 + 16 * wv + l15)) * 1024 + h_ * 64 + l4 * 8;
    const bf16x8 aq0 = ld_bf16x8(&qr[qoff]);
    const bf16x8 aq1 = ld_bf16x8(&qr[qoff + 32]);

    f32x4 accO[4];
#pragma unroll
    for (int dt = 0; dt < 4; ++dt) accO[dt] = fz;
    f32x4 lacc = fz;          // per-row sums via ones-MFMA (col-replicated)
    float mrun = -1e30f;      // wave-global running max

    // prologue: stage k-tile 0 into buffer 0
    {
#pragma unroll
      for (int i = 0; i < 2; ++i) {
        const int c = wv * 2 + i;
        const int row = c * 8 + srow;
        gload_lds16(kr + ((size_t)(b_ * SS + row)) * 1024 + h_ * 64 + scol,
                    (char*)&Ks[0][0] + c * 1024);
        gload_lds16(vT + ((size_t)(bh * 64 + row)) * SS + scol,
                    (char*)&Vs[0][0] + c * 1024);
      }
    }
    __syncthreads();

    int cur = 0;
    for (int kt = 0; kt <= j; ++kt) {
      // prefetch next k-tile into the other buffer (overlaps compute below)
      if (kt < j) {
        const int k0 = (kt + 1) * 64;
        const int nb = cur ^ 1;
#pragma unroll
        for (int i = 0; i < 2; ++i) {
          const int c = wv * 2 + i;
          const int row = c * 8 + srow;
          gload_lds16(kr + ((size_t)(b_ * SS + k0 + row)) * 1024 + h_ * 64 + scol,
                      (char*)&Ks[nb][0] + c * 1024);
          gload_lds16(vT + ((size_t)(bh * 64 + row)) * SS + k0 + scol,
                      (char*)&Vs[nb][0] + c * 1024);
        }
      }

      const bool diag = (kt == j);
      f32x4 sc[4];
      __builtin_amdgcn_s_setprio(1);
#pragma unroll
      for (int n = 0; n < 4; ++n) {
        if (!diag || n <= wv) {
          const int row = 16 * n + l15;
          const int sl0 = ((l4 + 0) ^ (l15 & 7)) * 8;
          const int sl1 = ((l4 + 4) ^ (l15 & 7)) * 8;
          bf16x8 kf0 = ld_bf16x8(&Ks[cur][row * 64 + sl0]);
          bf16x8 kf1 = ld_bf16x8(&Ks[cur][row * 64 + sl1]);
          sc[n] = __builtin_amdgcn_mfma_f32_16x16x32_bf16(aq0, kf0, fz, 0, 0, 0);
          sc[n] = __builtin_amdgcn_mfma_f32_16x16x32_bf16(aq1, kf1, sc[n], 0, 0, 0);
        } else {
          sc[n] = fz;   // fully-masked sub-tile; mask below sets -1e30
        }
      }
      __builtin_amdgcn_s_setprio(0);
      if (diag) {
#pragma unroll
        for (int n = 0; n < 4; ++n)
#pragma unroll
          for (int i = 0; i < 4; ++i) {
            const int kj = 16 * n + l15;
            const int qi = 16 * wv + 4 * l4 + i;
            if (kj > qi) sc[n][i] = -1e30f;
          }
      }

      // wave-global tile max: 15 in-register fmax (max3-fusable) + 6 shfl
      float t = sc[0][0];
#pragma unroll
      for (int n = 0; n < 4; ++n)
#pragma unroll
        for (int i = 0; i < 4; ++i) if (n || i) t = fmaxf(t, sc[n][i]);
      t = fmaxf(t, __shfl_xor(t, 1));
      t = fmaxf(t, __shfl_xor(t, 2));
      t = fmaxf(t, __shfl_xor(t, 4));
      t = fmaxf(t, __shfl_xor(t, 8));
      t = fmaxf(t, __shfl_xor(t, 16));
      t = fmaxf(t, __shfl_xor(t, 32));
      // defer-max (T13): rescale only when tile max grew by > 11 log2-units
      // (P then bounded by 2^11 = 2048 -- fine in bf16/f32 accum)
      if (t > mrun + 11.f) {     // wave-uniform after full butterfly
        const float alpha = exp2f(mrun - t);
        mrun = t;
        lacc *= alpha;
#pragma unroll
        for (int dt = 0; dt < 4; ++dt) accO[dt] *= alpha;
      }
      // P = exp2(sc - mrun) -> truncating bf16 -> per-wave swizzled LDS tile
#pragma unroll
      for (int n = 0; n < 4; ++n)
#pragma unroll
        for (int i = 0; i < 4; ++i) {
          const float pv = exp2f(sc[n][i] - mrun);
          const int r = 4 * l4 + i;
          const int cc = 16 * n + l15;
          const int phys = (cc >> 3) ^ (r & 7);
          Ps[wv][r * 64 + phys * 8 + (cc & 7)] =
              (unsigned short)(__float_as_uint(pv) >> 16);
        }
      __builtin_amdgcn_s_setprio(1);
#pragma unroll
      for (int kk = 0; kk < 2; ++kk) {
        if (diag && wv < 2 && kk == 1) continue;  // cols 32..63 all zero for waves 0,1
        const int psl = ((l4 + 4 * kk) ^ (l15 & 7)) * 8;
        bf16x8 pa = ld_bf16x8(&Ps[wv][l15 * 64 + psl]);
#pragma unroll
        for (int dt = 0; dt < 4; ++dt) {
          const int row = 16 * dt + l15;
          const int vsl = ((l4 + 4 * kk) ^ (l15 & 7)) * 8;
          bf16x8 vb = ld_bf16x8(&Vs[cur][row * 64 + vsl]);
          accO[dt] = __builtin_amdgcn_mfma_f32_16x16x32_bf16(pa, vb, accO[dt], 0, 0, 0);
        }
        // row-sum accumulator: D[q][*] += sum_k P[q,k] (ones B-operand)
        lacc = __builtin_amdgcn_mfma_f32_16x16x32_bf16(pa, ones, lacc, 0, 0, 0);
      }
      __builtin_amdgcn_s_setprio(0);
      __syncthreads();   // drains prefetch (vmcnt) + protects buffer reuse
      cur ^= 1;
    }

#pragma unroll
    for (int i = 0; i < 4; ++i) {
      const float inv = 1.0f / lacc[i];
      const size_t row = (size_t)(b_ * SS + q0 + 16 * wv + 4 * l4 + i);
#pragma unroll
      for (int dt = 0; dt < 4; ++dt)
        ao[row * 1024 + h_ * 64 + 16 * dt + l15] = f2bf(accO[dt][i] * inv);
    }
  }
}

extern "C" void kernel_launch(void* const* d_in, const int* in_sizes, int n_in,
                              void* d_out, int out_size, void* d_ws, size_t ws_size,
                              hipStream_t stream) {
  const float* Q  = (const float*)d_in[0];
  const float* K  = (const float*)d_in[1];
  const float* V  = (const float*)d_in[2];
  const float* Wq = (const float*)d_in[3];
  const float* bq = (const float*)d_in[4];
  const float* Wk = (const float*)d_in[5];
  const float* bk = (const float*)d_in[6];
  const float* Wv = (const float*)d_in[7];
  const float* bv = (const float*)d_in[8];
  const float* Wo = (const float*)d_in[9];
  const float* bo = (const float*)d_in[10];
  float* out = (float*)d_out;

  char* ws = (char*)d_ws;
  float2* tcs = (float2*)(ws);               // 512 KB interleaved cos/sin
  unsigned short* wqb = (unsigned short*)(ws + 512 * 1024);
  unsigned short* wkb = wqb + (1u << 20);
  unsigned short* wvb = wkb + (1u << 20);
  unsigned short* wob = wvb + (1u << 20);
  unsigned short* xb  = wob + (1u << 20);
  unsigned short* qrb = xb  + (size_t)MTOT * 1024;
  unsigned short* krb = qrb + (size_t)MTOT * 1024;
  unsigned short* vtb = krb + (size_t)MTOT * 1024;
  unsigned short* aob = vtb + (size_t)MTOT * 1024;

  k_rope_tables<<<256, 256, 0, stream>>>(tcs);
  k_cvt_bf16<<<1024, 256, 0, stream>>>(Wq, wqb, 1024 * 1024 / 4);
  k_cvt_bf16<<<1024, 256, 0, stream>>>(Wk, wkb, 1024 * 1024 / 4);
  k_cvt_bf16<<<1024, 256, 0, stream>>>(Wv, wvb, 1024 * 1024 / 4);
  k_cvt_bf16<<<1024, 256, 0, stream>>>(Wo, wob, 1024 * 1024 / 4);

  dim3 gg(MTOT / 128, 8);
  const float qsc = 0.125f * 1.4426950408889634f;  // fold 1/sqrt(64) and log2e

  k_cvt_bf16<<<MTOT * 1024 / 4 / 256, 256, 0, stream>>>(Q, xb, MTOT * 1024 / 4);
  k_gemm<E_ROPE><<<gg, 256, 0, stream>>>(xb, wqb, bq, qrb, tcs, qsc);
  k_cvt_bf16<<<MTOT * 1024 / 4 / 256, 256, 0, stream>>>(K, xb, MTOT * 1024 / 4);
  k_gemm<E_ROPE><<<gg, 256, 0, stream>>>(xb, wkb, bk, krb, tcs, 1.0f);
  k_cvt_bf16<<<MTOT * 1024 / 4 / 256, 256, 0, stream>>>(V, xb, MTOT * 1024 / 4);
  k_gemm<E_VT><<<gg, 256, 0, stream>>>(xb, wvb, bv, vtb, tcs, 1.0f);

  k_attn<<<64 * 16, 256, 0, stream>>>(qrb, krb, vtb, aob);

  k_gemm<E_F32><<<gg, 256, 0, stream>>>(aob, wob, bo, out, tcs, 1.0f);
}